// Round 8
// baseline (76.136 us; speedup 1.0000x reference)
//
#include <hip/hip_runtime.h>

// GAE reverse-scan, chunk-parallel (KCH=4) with 96-step decayed lookahead.
//   returns[t] = delta[t] + coef*returns[t+1], coef = 0.9405, coef^96 ~= 2.3e-3
// R8: max memory-level parallelism test. Scalar (1 col/thread) loads,
// 512 column-blocks x 4 time-chunks = 2048 blocks = 8 waves/CU, each wave
// holding 32 rows x 2 arrays = 16 KB in flight (UNR=32 double-buffer, fenced)
// -> 128 KB/CU outstanding, 2x R5. Store regions 256 rows each (8 units),
// lookahead 3 units; crit path 352 rows (= R7). NT stores (R6 showed cached
// stores regress).

#define T_STEPS 1024
#define BATCH   32768
#define UNR     32           // rows per register chunk (one "unit")

__global__ __launch_bounds__(64) void gae_kernel(const float* __restrict__ rewards,
                                                 const float* __restrict__ values,
                                                 float* __restrict__ out) {
    const int cb  = blockIdx.x & 511;       // 512 column-blocks (64 cols each)
    const int k   = blockIdx.x >> 9;        // time-chunk id 0..3
    const int col = cb * 64 + (int)threadIdx.x;

    const float coefK = 0.99f * 0.05f;      // DISCOUNT * (1 - LAMMDA)
    const float coef  = 0.99f * 0.95f;      // DISCOUNT * LAMMDA

    const float* rp = rewards + col;
    const float* vp = values  + col;        // values[t+1] -> vp[(t+1)*BATCH]
    float*       op = out + col;

    float rA[UNR], vA[UNR], rB[UNR], vB[UNR];
    float acc = 0.f;

    const int base = k * 8;                 // first store unit (32-row units)

// Load 32-row unit C (descending i; compile-time register indices only).
#define LOADC(RR, VV, C)                                                    \
    {                                                                       \
        const int t0_ = (C) * UNR;                                          \
        _Pragma("unroll")                                                   \
        for (int i = UNR - 1; i >= 0; --i) {                                \
            RR[i] = rp[(size_t)(t0_ + i) * BATCH];                          \
            VV[i] = vp[(size_t)(t0_ + i + 1) * BATCH];                      \
        }                                                                   \
    }

// Consume unit C descending; ST is a compile-time store flag.
#define COMPC(RR, VV, C, ST)                                                \
    {                                                                       \
        const int t0_ = (C) * UNR;                                          \
        _Pragma("unroll")                                                   \
        for (int i = UNR - 1; i >= 0; --i) {                                \
            float d_ = fmaf(coefK, VV[i], RR[i]);                           \
            acc = fmaf(coef, acc, d_);                                      \
            if (ST)                                                         \
                __builtin_nontemporal_store(acc, &op[(size_t)(t0_ + i) * BATCH]); \
        }                                                                   \
    }

// Pipelined unit: prefetch unit PC into NXT regs, fence, compute CUR unit C.
#define STEPU(CR, CV, NR, NV, C, PC, ST)                                    \
    {                                                                       \
        LOADC(NR, NV, PC);                                                  \
        __builtin_amdgcn_sched_barrier(0);                                  \
        COMPC(CR, CV, C, ST);                                               \
    }

    if (k < 3) {
        // 3 lookahead units (base+10..base+8), then 8 store units (base+7..base).
        LOADC(rA, vA, base + 10);
        STEPU(rA, vA, rB, vB, base + 10, base + 9, 0);
        STEPU(rB, vB, rA, vA, base + 9,  base + 8, 0);
        STEPU(rA, vA, rB, vB, base + 8,  base + 7, 0);
        STEPU(rB, vB, rA, vA, base + 7,  base + 6, 1);
        STEPU(rA, vA, rB, vB, base + 6,  base + 5, 1);
        STEPU(rB, vB, rA, vA, base + 5,  base + 4, 1);
        STEPU(rA, vA, rB, vB, base + 4,  base + 3, 1);
        STEPU(rB, vB, rA, vA, base + 3,  base + 2, 1);
        STEPU(rA, vA, rB, vB, base + 2,  base + 1, 1);
        STEPU(rB, vB, rA, vA, base + 1,  base + 0, 1);
        __builtin_amdgcn_sched_barrier(0);
        COMPC(rA, vA, base + 0, 1);
    } else {
        // Last time-chunk: true suffix start, 8 store units (base+7..base).
        LOADC(rA, vA, base + 7);
        STEPU(rA, vA, rB, vB, base + 7, base + 6, 1);
        STEPU(rB, vB, rA, vA, base + 6, base + 5, 1);
        STEPU(rA, vA, rB, vB, base + 5, base + 4, 1);
        STEPU(rB, vB, rA, vA, base + 4, base + 3, 1);
        STEPU(rA, vA, rB, vB, base + 3, base + 2, 1);
        STEPU(rB, vB, rA, vA, base + 2, base + 1, 1);
        STEPU(rA, vA, rB, vB, base + 1, base + 0, 1);
        __builtin_amdgcn_sched_barrier(0);
        COMPC(rB, vB, base + 0, 1);
    }

#undef LOADC
#undef COMPC
#undef STEPU
}

extern "C" void kernel_launch(void* const* d_in, const int* in_sizes, int n_in,
                              void* d_out, int out_size, void* d_ws, size_t ws_size,
                              hipStream_t stream) {
    const float* rewards = (const float*)d_in[0];
    const float* values  = (const float*)d_in[1];
    float* out = (float*)d_out;

    const int grid = 4 * (BATCH / 64);      // 2048 blocks, 8 waves/CU
    gae_kernel<<<grid, 64, 0, stream>>>(rewards, values, out);
}

// Round 9
// 73.730 us; speedup vs baseline: 1.0326x; 1.0326x over previous
//
#include <hip/hip_runtime.h>

// GAE reverse-scan, chunk-parallel (KCH=4) with 96-step decayed lookahead.
//   returns[t] = delta[t] + coef*returns[t+1], coef = 0.9405, coef^96 ~= 2.3e-3
// R9: DRAM page-locality test. block=256 (4 waves), float2 -> each block owns
// 512 contiguous cols and one row-visit issues 2 KB contiguous (4 x 512 B),
// phase-locked by a raw s_barrier per unit (NOT __syncthreads - that drains
// vmcnt and collapses the double-buffer). 64 col-blocks x 4 chunks = 256
// blocks = 1 block/CU, 64 KB/CU in flight (UNR=16 fenced double-buffer).
// Geometry = R7: store {224,224,224,352} rows, LOOK=96, crit path 352 rows.

#define T_STEPS 1024
#define BATCH   32768
#define UNR     16           // rows per register unit

typedef float f2 __attribute__((ext_vector_type(2)));

__global__ __launch_bounds__(256) void gae_kernel(const float* __restrict__ rewards,
                                                  const float* __restrict__ values,
                                                  float* __restrict__ out) {
    const int cb  = blockIdx.x & 63;        // 64 column-blocks (512 cols each)
    const int k   = blockIdx.x >> 6;        // time-chunk id 0..3
    const int col = cb * 512 + (int)threadIdx.x * 2;

    const float coefK = 0.99f * 0.05f;      // DISCOUNT * (1 - LAMMDA)
    const float coef  = 0.99f * 0.95f;      // DISCOUNT * LAMMDA

    const f2* rp = (const f2*)(rewards + col);
    const f2* vp = (const f2*)(values  + col);   // values[t+1] -> vp[(t+1)*RS]
    f2*       op = (f2*)(out + col);
    const size_t RS = BATCH / 2;            // row stride in float2 units

    f2 rA[UNR], vA[UNR], rB[UNR], vB[UNR];
    f2 acc = {0.f, 0.f};

// Load 16-row unit C (descending i; compile-time register indices only).
#define LOADC(RR, VV, C)                                                    \
    {                                                                       \
        const int t0_ = (C) * UNR;                                          \
        _Pragma("unroll")                                                   \
        for (int i = UNR - 1; i >= 0; --i) {                                \
            RR[i] = rp[(size_t)(t0_ + i) * RS];                             \
            VV[i] = vp[(size_t)(t0_ + i + 1) * RS];                         \
        }                                                                   \
    }

// Consume unit C descending; ST is a compile-time store flag.
#define COMPC(RR, VV, C, ST)                                                \
    {                                                                       \
        const int t0_ = (C) * UNR;                                          \
        _Pragma("unroll")                                                   \
        for (int i = UNR - 1; i >= 0; --i) {                                \
            f2 d_;                                                          \
            d_.x = fmaf(coefK, VV[i].x, RR[i].x);                           \
            d_.y = fmaf(coefK, VV[i].y, RR[i].y);                           \
            acc.x = fmaf(coef, acc.x, d_.x);                                \
            acc.y = fmaf(coef, acc.y, d_.y);                                \
            if (ST)                                                         \
                __builtin_nontemporal_store(acc, &op[(size_t)(t0_ + i) * RS]); \
        }                                                                   \
    }

    // Store-region geometry in 16-row units (same as R7):
    //   k<3: base = 14*k, topS = base+13 (14 units), lookahead topS+1..topS+6
    //   k=3: base = 42,   topS = 63      (22 units), no lookahead
    int base, topS, c;
    if (k < 3) {
        base = k * 14;
        topS = base + 13;
        LOADC(rA, vA, topS + 6);
        for (c = topS + 6; c >= topS + 2; c -= 2) {
            __builtin_amdgcn_s_barrier();   // phase-lock the 4 waves' loads
            LOADC(rB, vB, c - 1);
            __builtin_amdgcn_sched_barrier(0);
            COMPC(rA, vA, c, 0);
            __builtin_amdgcn_s_barrier();
            LOADC(rA, vA, c - 2);           // final iter loads unit topS
            __builtin_amdgcn_sched_barrier(0);
            COMPC(rB, vB, c - 1, 0);
        }
    } else {
        base = 42;
        topS = 63;
        LOADC(rA, vA, topS);
    }

    // Store region: topS .. base (even unit count in both branches).
    for (c = topS; c >= base + 1; c -= 2) {
        __builtin_amdgcn_s_barrier();
        LOADC(rB, vB, c - 1);
        __builtin_amdgcn_sched_barrier(0);
        COMPC(rA, vA, c, 1);
        __builtin_amdgcn_s_barrier();
        if (c >= base + 3) LOADC(rA, vA, c - 2);
        __builtin_amdgcn_sched_barrier(0);
        COMPC(rB, vB, c - 1, 1);
    }

#undef LOADC
#undef COMPC
}

extern "C" void kernel_launch(void* const* d_in, const int* in_sizes, int n_in,
                              void* d_out, int out_size, void* d_ws, size_t ws_size,
                              hipStream_t stream) {
    const float* rewards = (const float*)d_in[0];
    const float* values  = (const float*)d_in[1];
    float* out = (float*)d_out;

    const int grid = 4 * (BATCH / 512);     // 256 blocks, 1 block/CU, 4 waves
    gae_kernel<<<grid, 256, 0, stream>>>(rewards, values, out);
}